// Round 6
// baseline (3602.873 us; speedup 1.0000x reference)
//
#include <hip/hip_runtime.h>
#include <math.h>

// ---- geometry constants (match reference) ----
#define NA   24
#define NU   128
#define NV   64
#define NW   128   // volume W (x)
#define NH   128   // volume H (y)
#define ND   64    // volume D (z)
#define NS   128   // samples per ray
#define F_STEP 1.5625f            // 2*HS/S = 200/128
#define F_DL  (200.0f / 127.0f)   // linspace(156,356,128) spacing
#define F_L0  156.0f
#define INV_DL (127.0f / 200.0f)

#define NRAYS (NA * NV * NU)      // 196608
#define VOX   (NW * NH * ND)      // 1048576

typedef float v2f __attribute__((ext_vector_type(2)));

// Per-ray geometry for FP.
__device__ __forceinline__ void ray_setup(int a, int v, int u,
                                          float& sx, float& sy,
                                          float& dx, float& dy, float& dz) {
    float ang = (float)((double)a * (15.0 * M_PI / 180.0));
    float c = cosf(ang), s = sinf(ang);
    float uu = (float)u - 63.5f;
    float vv = (float)v - 31.5f;
    float ux = 512.0f * c - uu * s;
    float uy = 512.0f * s + uu * c;
    float uz = vv;
    float invn = 1.0f / sqrtf(ux * ux + uy * uy + uz * uz);
    dx = ux * invn; dy = uy * invn; dz = uz * invn;
    sx = -256.0f * c; sy = -256.0f * s;
}

// ---------------- forward projection, segmented over ell ----------------
__global__ __launch_bounds__(256) void fp_seg_kernel(const float* __restrict__ vol,
                                                     float* __restrict__ part) {
    int r = blockIdx.x * blockDim.x + threadIdx.x;
    int seg = blockIdx.y;
    int u = r & (NU - 1);
    int v = (r >> 7) & (NV - 1);
    int a = r >> 13;

    float sx, sy, dx, dy, dz;
    ray_setup(a, v, u, sx, sy, dx, dy, dz);

    float rx = 1.0f / dx, ry = 1.0f / dy, rz = 1.0f / dz;
    float ex0 = (-64.55f - sx) * rx, ex1 = (64.55f - sx) * rx;
    float ey0 = (-64.55f - sy) * ry, ey1 = (64.55f - sy) * ry;
    float ez0 = (-32.55f) * rz,      ez1 = (32.55f) * rz;
    float llo = fmaxf(fmaxf(fminf(ex0, ex1), fminf(ey0, ey1)), fminf(ez0, ez1));
    float lhi = fminf(fminf(fmaxf(ex0, ex1), fmaxf(ey0, ey1)), fmaxf(ez0, ez1));
    int i_lo = max(seg * 64,      (int)ceilf((llo - F_L0) * INV_DL));
    int i_hi = min(seg * 64 + 63, (int)floorf((lhi - F_L0) * INV_DL));

    float acc = 0.0f;
    for (int i = i_lo; i <= i_hi; ++i) {
        float ell = F_L0 + F_DL * (float)i;
        float cx = sx + ell * dx + 63.5f;
        float cy = sy + ell * dy + 63.5f;
        float cz =      ell * dz + 31.5f;
        float fx = floorf(cx), fy = floorf(cy), fz = floorf(cz);
        int ix = (int)fx, iy = (int)fy, iz = (int)fz;
        float wx1 = cx - fx, wy1 = cy - fy, wz1 = cz - fz;
        float wx0 = 1.0f - wx1, wy0 = 1.0f - wy1, wz0 = 1.0f - wz1;
        bool bx0 = (unsigned)ix < NW,      bx1 = (unsigned)(ix + 1) < NW;
        bool by0 = (unsigned)iy < NH,      by1 = (unsigned)(iy + 1) < NH;
        bool bz0 = (unsigned)iz < ND,      bz1 = (unsigned)(iz + 1) < ND;
        long base = ((long)iz * NH + iy) * NW + ix;
        float v000 = (bz0 && by0 && bx0) ? vol[base]                 : 0.0f;
        float v001 = (bz0 && by0 && bx1) ? vol[base + 1]             : 0.0f;
        float v010 = (bz0 && by1 && bx0) ? vol[base + NW]            : 0.0f;
        float v011 = (bz0 && by1 && bx1) ? vol[base + NW + 1]        : 0.0f;
        float v100 = (bz1 && by0 && bx0) ? vol[base + NH * NW]       : 0.0f;
        float v101 = (bz1 && by0 && bx1) ? vol[base + NH * NW + 1]   : 0.0f;
        float v110 = (bz1 && by1 && bx0) ? vol[base + NH * NW + NW]  : 0.0f;
        float v111 = (bz1 && by1 && bx1) ? vol[base + NH * NW + NW + 1] : 0.0f;
        acc += wz0 * (wy0 * (wx0 * v000 + wx1 * v001) +
                      wy1 * (wx0 * v010 + wx1 * v011)) +
               wz1 * (wy0 * (wx0 * v100 + wx1 * v101) +
                      wy1 * (wx0 * v110 + wx1 * v111));
    }
    part[seg * NRAYS + r] = acc;
}

// ---------------- residual + cosine weight + Ram-Lak along u ----------------
__global__ __launch_bounds__(NU) void ramp_kernel(const float* __restrict__ part,
                                                  const float* __restrict__ p,
                                                  float* __restrict__ res) {
    __shared__ float row[NU];
    int rowid = blockIdx.x;          // a*NV + v
    int u = threadIdx.x;
    int e = rowid * NU + u;
    int v = rowid & (NV - 1);
    float sino = (part[e] + part[NRAYS + e]) * F_STEP;
    double du = (double)u - 64.0;
    double dv = (double)v - 32.0;
    float cw = (float)(512.0 / sqrt(262144.0 + dv * dv + du * du));
    row[u] = (sino - p[e]) * cw;
    __syncthreads();
    float acc = 0.125f * row[u];
#pragma unroll
    for (int d = 1; d <= 63; d += 2) {
        float f = (float)(-0.5 / (M_PI * M_PI * (double)(d * d)));
        float lo = (u - d >= 0) ? row[u - d] : 0.0f;
        float hi = (u + d < NU) ? row[u + d] : 0.0f;
        acc += f * (lo + hi);
    }
    res[e] = acc;
}

// ---------------- back projection: ray-driven scatter into LDS tiles ----------------
// Block = (volume tile 32x16x16, angle-group of 6 angles spaced 60deg).
// LDS tile has a 1-cell pad border (34x18x18): out-of-tile trilinear corners land
// in pad cells, discarded at writeout -> no masking, no global atomics.
// Each (tile,group) block writes its disjoint region of buf[group]; reduce sums.
#define TSX 32
#define TSY 16
#define TSZ 16
#define PX  34
#define PY  18
#define PZ  18
#define TILE_N (PX * PY * PZ)     // 11016
#define NGROUP 4

__global__ __launch_bounds__(512, 4) void bp_scatter(const float* __restrict__ res,
                                                     float* __restrict__ bufs) {
    __shared__ float T[TILE_N + 48];   // +48 guard for 1-ulp slab overshoot at the corner

    const int tid  = threadIdx.x;
    const int lane = tid & 63;
    const int wv   = tid >> 6;         // 0..7
    const int tile = blockIdx.x & 127;
    const int g    = blockIdx.x >> 7;  // 0..3
    const int X0 = (tile & 3) * TSX;
    const int Y0 = ((tile >> 2) & 7) * TSY;
    const int Z0 = (tile >> 5) * TSZ;

    for (int t = tid; t < TILE_N + 48; t += 512) T[t] = 0.0f;
    __syncthreads();

    // expanded box in centered coords (for footprint projection)
    const float bxl = (float)X0 - 1.0f - 63.5f, bxh = (float)X0 + TSX - 63.5f;
    const float byl = (float)Y0 - 1.0f - 63.5f, byh = (float)Y0 + TSY - 63.5f;
    const float bzl = (float)Z0 - 1.0f - 31.5f, bzh = (float)Z0 + TSZ - 31.5f;

    for (int j = 0; j < NA / NGROUP; ++j) {
        const int a = g + NGROUP * j;                 // angles spaced 60 deg
        float ang = (float)((double)a * (15.0 * M_PI / 180.0));
        const float c  = cosf(ang);
        const float sn = sinf(ang);

        // exact detector footprint of the expanded box (8 corners)
        float uumin = 1e30f, uumax = -1e30f, vvmin = 1e30f, vvmax = -1e30f;
#pragma unroll
        for (int k = 0; k < 8; ++k) {
            float xc = (k & 1) ? bxh : bxl;
            float yc = (k & 2) ? byh : byl;
            float zc = (k & 4) ? bzh : bzl;
            float rho = fmaf(xc, c, fmaf(yc, sn, 256.0f));   // > 0 always
            float ir  = __builtin_amdgcn_rcpf(rho);
            float uu  = 512.0f * (yc * c - xc * sn) * ir;
            float vv  = 512.0f * zc * ir;
            uumin = fminf(uumin, uu); uumax = fmaxf(uumax, uu);
            vvmin = fminf(vvmin, vv); vvmax = fmaxf(vvmax, vv);
        }
        const int u_lo = max(0,   (int)ceilf(uumin + 63.48f));
        const int u_hi = min(127, (int)floorf(uumax + 63.52f));
        const int v_lo = max(0,  (int)ceilf(vvmin + 31.48f));
        const int v_hi = min(63, (int)floorf(vvmax + 31.52f));
        if (u_lo > u_hi || v_lo > v_hi) continue;

        // source in index coords, shifted to padded-local: local = idx - X0 + 1
        const float sxl = 63.5f - 256.0f * c - (float)X0 + 1.0f;
        const float syl = 63.5f - 256.0f * sn - (float)Y0 + 1.0f;
        const float szl = 31.5f - (float)Z0 + 1.0f;
        // slab bounds in padded-local coords: (0, TS+2)
        const float c512 = 512.0f * c;
        const float s512 = 512.0f * sn;
        const float* resa = res + (a << 13);

        for (int v = v_lo + wv; v <= v_hi; v += 8) {
            const float vvf = (float)v - 31.5f;
            const float* resrow = resa + (v << 7);
            for (int ub = u_lo; ub <= u_hi; ub += 64) {
                const int u = ub + lane;
                if (u > u_hi) continue;
                const float uuf = (float)u - 63.5f;
                const float pu = fmaf(-uuf, sn, c512);
                const float qu = fmaf(uuf, c, s512);
                const float arg = fmaf(uuf, uuf, fmaf(vvf, vvf, 262144.0f));
                const float invn = __builtin_amdgcn_rsqf(arg);
                const float dxn = pu * invn, dyn = qu * invn, dzn = vvf * invn;
                // slab test in padded-local coords
                const float rx = __builtin_amdgcn_rcpf(dxn);
                const float ry = __builtin_amdgcn_rcpf(dyn);
                const float rz = __builtin_amdgcn_rcpf(dzn);
                const float ax = (0.0f - sxl) * rx, bx = ((float)(TSX + 2) - sxl) * rx;
                const float ay = (0.0f - syl) * ry, by = ((float)(TSY + 2) - syl) * ry;
                const float az = (0.0f - szl) * rz, bz = ((float)(TSZ + 2) - szl) * rz;
                const float llo = fmaxf(fmaxf(fminf(ax, bx), fminf(ay, by)), fminf(az, bz));
                const float lhi = fminf(fminf(fmaxf(ax, bx), fmaxf(ay, by)), fmaxf(az, bz));
                int i0 = max(0,   (int)ceilf((llo - F_L0) * INV_DL));
                int i1 = min(127, (int)floorf((lhi - F_L0) * INV_DL));
                if (i0 > i1) continue;
                const float rv = resrow[u];
                float ell = fmaf((float)i0, F_DL, F_L0);
                for (int i = i0; i <= i1; ++i, ell += F_DL) {
                    const float lx = fmaf(ell, dxn, sxl);
                    const float ly = fmaf(ell, dyn, syl);
                    const float lz = fmaf(ell, dzn, szl);
                    const float fx = floorf(lx), fy = floorf(ly), fz = floorf(lz);
                    const float wx1 = lx - fx, wy1 = ly - fy, wz1 = lz - fz;
                    const float wx0 = 1.0f - wx1, wy0 = 1.0f - wy1, wz0 = 1.0f - wz1;
                    const int ix = (int)fx, iy = (int)fy, iz = (int)fz;
                    const int base = (iz * PY + iy) * PX + ix;
                    const float a0 = wx0 * rv, a1 = wx1 * rv;
                    const float c00 = wy0 * wz0, c01 = wy1 * wz0;
                    const float c10 = wy0 * wz1, c11 = wy1 * wz1;
                    atomicAdd(&T[base],               a0 * c00);
                    atomicAdd(&T[base + 1],           a1 * c00);
                    atomicAdd(&T[base + PX],          a0 * c01);
                    atomicAdd(&T[base + PX + 1],      a1 * c01);
                    atomicAdd(&T[base + PX * PY],     a0 * c10);
                    atomicAdd(&T[base + PX * PY + 1], a1 * c10);
                    atomicAdd(&T[base + PX * PY + PX],     a0 * c11);
                    atomicAdd(&T[base + PX * PY + PX + 1], a1 * c11);
                }
            }
        }
    }
    __syncthreads();

    // write interior region (discard pads) into this group's buffer — plain stores
    float* bg = bufs + g * VOX;
    for (int t = tid; t < TSX * TSY * TSZ; t += 512) {
        int lx = t & (TSX - 1);
        int ly = (t >> 5) & (TSY - 1);
        int lz = t >> 9;
        float val = T[((lz + 1) * PY + (ly + 1)) * PX + lx + 1];
        bg[((Z0 + lz) << 14) + ((Y0 + ly) << 7) + X0 + lx] = val;
    }
}

__global__ __launch_bounds__(256) void reduce_kernel(const float* __restrict__ bufs,
                                                     float* __restrict__ out) {
    int i = blockIdx.x * blockDim.x + threadIdx.x;   // float4 index
    const float4* b0 = (const float4*)bufs;
    const float4* b1 = (const float4*)(bufs + VOX);
    const float4* b2 = (const float4*)(bufs + 2 * VOX);
    const float4* b3 = (const float4*)(bufs + 3 * VOX);
    float4 r0 = b0[i], r1 = b1[i], r2 = b2[i], r3 = b3[i];
    float4 o;
    o.x = (r0.x + r1.x + r2.x + r3.x) * F_STEP;
    o.y = (r0.y + r1.y + r2.y + r3.y) * F_STEP;
    o.z = (r0.z + r1.z + r2.z + r3.z) * F_STEP;
    o.w = (r0.w + r1.w + r2.w + r3.w) * F_STEP;
    ((float4*)out)[i] = o;
}

// ---------------- fallback gather BP (R5) if ws too small ----------------
#define RES_PITCH 129
__global__ __launch_bounds__(512, 8) void bp_gather4(const float* __restrict__ res,
                                                     float* __restrict__ out) {
    __shared__ float s_res[NV * RES_PITCH];
    const int tid = threadIdx.x;
    const int xi  = tid & 127;
    const int rr  = tid >> 7;
    const int yb  = blockIdx.x & 127;
    const int zb  = blockIdx.x >> 7;
    const int yi  = (yb + 32 * rr) & 127;
    const int zi  = zb + 16 * rr;
    const float x0 = (float)xi - 63.5f;
    const float y0 = (float)yi - 63.5f;
    const float z0 = (float)zi - 31.5f;
    const float Az = z0 - 1.01f, Bz = z0 + 1.01f;
    const bool  sAz = (Az >= 0.0f), sBz = (Bz >= 0.0f);
    const float zz2 = z0 * z0;
    v2f acc = {0.0f, 0.0f};
    for (int a = 0; a < NA; ++a) {
        __syncthreads();
        const float* ra = res + a * (NV * NU);
#pragma unroll
        for (int k = 0; k < 16; ++k) {
            int e = tid + (k << 9);
            s_res[(e >> 7) * RES_PITCH + (e & 127)] = ra[e];
        }
        __syncthreads();
        float ang = (float)((double)a * (15.0 * M_PI / 180.0));
        const float c  = cosf(ang);
        const float sn = sinf(ang);
        const float c512 = 512.0f * c;
        const float s512 = 512.0f * sn;
        const float ab1  = fabsf(c) + fabsf(sn);
        const float Vx  = x0 + 256.0f * c;
        const float Vy  = y0 + 256.0f * sn;
        const float Vxm = Vx - 1.0f, Vxp = Vx + 1.0f;
        const float Vym = Vy - 1.0f, Vyp = Vy + 1.0f;
        const float ellc = sqrtf(fmaf(Vx, Vx, fmaf(Vy, Vy, zz2)));
        const float tvlo = (ellc - 1.785f) * (1.0f / 517.0f);
        const float tvhi = (ellc + 1.785f) * (1.0f / 512.0f);
        const float itlo = __builtin_amdgcn_rcpf(tvlo);
        const float ithi = __builtin_amdgcn_rcpf(tvhi);
        const float yp = y0 * c - x0 * sn;
        const float A = yp - ab1, B = yp + ab1;
        const float uumin = A * ((A >= 0.0f) ? ithi : itlo);
        const float uumax = B * ((B >= 0.0f) ? itlo : ithi);
        const int u_lo = max(0,   (int)ceilf(uumin + 63.49f));
        const int u_hi = min(127, (int)floorf(uumax + 63.51f));
        float uuf = (float)u_lo - 63.5f;
        for (int u = u_lo; u <= u_hi; ++u, uuf += 1.0f) {
            const float pu = fmaf(-uuf, sn, c512);
            const float qu = fmaf(uuf, c, s512);
            const float rp = __builtin_amdgcn_rcpf(pu);
            const float rq = __builtin_amdgcn_rcpf(qu);
            const float ax = Vxm * rp, bx = Vxp * rp;
            const float ay = Vym * rq, by = Vyp * rq;
            const float tl = fmaxf(fmaxf(fminf(ax, bx), fminf(ay, by)), tvlo);
            const float th = fminf(fminf(fmaxf(ax, bx), fmaxf(ay, by)), tvhi);
            if (tl < th) {
                const float rtl = __builtin_amdgcn_rcpf(tl);
                const float rth = __builtin_amdgcn_rcpf(th);
                const float vminf_ = Az * (sAz ? rth : rtl);
                const float vmaxf_ = Bz * (sBz ? rtl : rth);
                const int v_lo = max(0,  (int)ceilf(vminf_ + 31.49f));
                const int v_hi = min(63, (int)floorf(vmaxf_ + 31.51f));
                const float c1u  = fmaf(uuf, uuf, 262144.0f);
                const float tlDL = tl * INV_DL;
                float vvf = (float)v_lo - 31.5f;
                for (int v = v_lo; v <= v_hi; ++v, vvf += 1.0f) {
                    const float arg  = fmaf(vvf, vvf, c1u);
                    const float invn = __builtin_amdgcn_rsqf(arg);
                    const float nn   = arg * invn;
                    const float rv   = s_res[v * RES_PITCH + u];
                    const float i0f  = ceilf(fmaf(tlDL, nn, -(F_L0 * INV_DL) - 1.0e-3f));
                    const float ell0 = fmaf(i0f, F_DL, F_L0);
                    v2f tp;
                    tp.x = ell0 * invn;
                    tp.y = fmaf(F_DL, invn, tp.x);
                    const v2f pu2 = {pu, pu}, qu2 = {qu, qu}, vv2 = {vvf, vvf};
                    const v2f mVx = {-Vx, -Vx}, mVy = {-Vy, -Vy}, mz0 = {-z0, -z0};
                    const v2f one2 = {1.0f, 1.0f}, zero2 = {0.0f, 0.0f};
                    v2f wx = __builtin_elementwise_max(
                        one2 - __builtin_elementwise_abs(__builtin_elementwise_fma(tp, pu2, mVx)), zero2);
                    v2f wy = __builtin_elementwise_max(
                        one2 - __builtin_elementwise_abs(__builtin_elementwise_fma(tp, qu2, mVy)), zero2);
                    v2f wz = __builtin_elementwise_max(
                        one2 - __builtin_elementwise_abs(__builtin_elementwise_fma(tp, vv2, mz0)), zero2);
                    const v2f w = wx * wy * wz;
                    const v2f rv2 = {rv, rv};
                    acc = __builtin_elementwise_fma(w, rv2, acc);
                }
            }
        }
    }
    out[(zi << 14) + (yi << 7) + xi] = (acc.x + acc.y) * F_STEP;
}

extern "C" void kernel_launch(void* const* d_in, const int* in_sizes, int n_in,
                              void* d_out, int out_size, void* d_ws, size_t ws_size,
                              hipStream_t stream) {
    const float* x = (const float*)d_in[0];   // [1,1,64,128,128]
    const float* p = (const float*)d_in[1];   // [1,1,24,64,128]
    float* out  = (float*)d_out;              // [1,1,64,128,128]
    float* res  = (float*)d_ws;               // filtered residual, NRAYS floats
    float* part = res + NRAYS;                // 2 FP segments, 2*NRAYS floats
    float* bufs = part + 2 * NRAYS;           // 4 privatization volumes, 4*VOX floats

    const size_t need = (size_t)(3 * NRAYS + NGROUP * VOX) * sizeof(float);

    dim3 fpg(NRAYS / 256, 2);
    fp_seg_kernel<<<fpg, 256, 0, stream>>>(x, part);
    ramp_kernel<<<NA * NV, NU, 0, stream>>>(part, p, res);
    if (ws_size >= need) {
        bp_scatter<<<128 * NGROUP, 512, 0, stream>>>(res, bufs);
        reduce_kernel<<<VOX / 4 / 256, 256, 0, stream>>>(bufs, out);
    } else {
        bp_gather4<<<(NW * NH * ND) / 512, 512, 0, stream>>>(res, out);
    }
}

// Round 7
// 2156.671 us; speedup vs baseline: 1.6706x; 1.6706x over previous
//
#include <hip/hip_runtime.h>
#include <math.h>

// ---- geometry constants (match reference) ----
#define NA   24
#define NU   128
#define NV   64
#define NW   128   // volume W (x)
#define NH   128   // volume H (y)
#define ND   64    // volume D (z)
#define NS   128   // samples per ray
#define F_STEP 1.5625f            // 2*HS/S = 200/128
#define F_DL  (200.0f / 127.0f)   // linspace(156,356,128) spacing
#define F_L0  156.0f
#define INV_DL (127.0f / 200.0f)

#define NRAYS (NA * NV * NU)      // 196608
#define VOX   (NW * NH * ND)      // 1048576

typedef float v2f __attribute__((ext_vector_type(2)));

// Per-ray geometry for FP.
__device__ __forceinline__ void ray_setup(int a, int v, int u,
                                          float& sx, float& sy,
                                          float& dx, float& dy, float& dz) {
    float ang = (float)((double)a * (15.0 * M_PI / 180.0));
    float c = cosf(ang), s = sinf(ang);
    float uu = (float)u - 63.5f;
    float vv = (float)v - 31.5f;
    float ux = 512.0f * c - uu * s;
    float uy = 512.0f * s + uu * c;
    float uz = vv;
    float invn = 1.0f / sqrtf(ux * ux + uy * uy + uz * uz);
    dx = ux * invn; dy = uy * invn; dz = uz * invn;
    sx = -256.0f * c; sy = -256.0f * s;
}

// ---------------- forward projection, segmented over ell ----------------
__global__ __launch_bounds__(256) void fp_seg_kernel(const float* __restrict__ vol,
                                                     float* __restrict__ part) {
    int r = blockIdx.x * blockDim.x + threadIdx.x;
    int seg = blockIdx.y;
    int u = r & (NU - 1);
    int v = (r >> 7) & (NV - 1);
    int a = r >> 13;

    float sx, sy, dx, dy, dz;
    ray_setup(a, v, u, sx, sy, dx, dy, dz);

    float rx = 1.0f / dx, ry = 1.0f / dy, rz = 1.0f / dz;
    float ex0 = (-64.55f - sx) * rx, ex1 = (64.55f - sx) * rx;
    float ey0 = (-64.55f - sy) * ry, ey1 = (64.55f - sy) * ry;
    float ez0 = (-32.55f) * rz,      ez1 = (32.55f) * rz;
    float llo = fmaxf(fmaxf(fminf(ex0, ex1), fminf(ey0, ey1)), fminf(ez0, ez1));
    float lhi = fminf(fminf(fmaxf(ex0, ex1), fmaxf(ey0, ey1)), fmaxf(ez0, ez1));
    int i_lo = max(seg * 64,      (int)ceilf((llo - F_L0) * INV_DL));
    int i_hi = min(seg * 64 + 63, (int)floorf((lhi - F_L0) * INV_DL));

    float acc = 0.0f;
    for (int i = i_lo; i <= i_hi; ++i) {
        float ell = F_L0 + F_DL * (float)i;
        float cx = sx + ell * dx + 63.5f;
        float cy = sy + ell * dy + 63.5f;
        float cz =      ell * dz + 31.5f;
        float fx = floorf(cx), fy = floorf(cy), fz = floorf(cz);
        int ix = (int)fx, iy = (int)fy, iz = (int)fz;
        float wx1 = cx - fx, wy1 = cy - fy, wz1 = cz - fz;
        float wx0 = 1.0f - wx1, wy0 = 1.0f - wy1, wz0 = 1.0f - wz1;
        bool bx0 = (unsigned)ix < NW,      bx1 = (unsigned)(ix + 1) < NW;
        bool by0 = (unsigned)iy < NH,      by1 = (unsigned)(iy + 1) < NH;
        bool bz0 = (unsigned)iz < ND,      bz1 = (unsigned)(iz + 1) < ND;
        long base = ((long)iz * NH + iy) * NW + ix;
        float v000 = (bz0 && by0 && bx0) ? vol[base]                 : 0.0f;
        float v001 = (bz0 && by0 && bx1) ? vol[base + 1]             : 0.0f;
        float v010 = (bz0 && by1 && bx0) ? vol[base + NW]            : 0.0f;
        float v011 = (bz0 && by1 && bx1) ? vol[base + NW + 1]        : 0.0f;
        float v100 = (bz1 && by0 && bx0) ? vol[base + NH * NW]       : 0.0f;
        float v101 = (bz1 && by0 && bx1) ? vol[base + NH * NW + 1]   : 0.0f;
        float v110 = (bz1 && by1 && bx0) ? vol[base + NH * NW + NW]  : 0.0f;
        float v111 = (bz1 && by1 && bx1) ? vol[base + NH * NW + NW + 1] : 0.0f;
        acc += wz0 * (wy0 * (wx0 * v000 + wx1 * v001) +
                      wy1 * (wx0 * v010 + wx1 * v011)) +
               wz1 * (wy0 * (wx0 * v100 + wx1 * v101) +
                      wy1 * (wx0 * v110 + wx1 * v111));
    }
    part[seg * NRAYS + r] = acc;
}

// ---------------- residual + cosine weight + Ram-Lak along u ----------------
__global__ __launch_bounds__(NU) void ramp_kernel(const float* __restrict__ part,
                                                  const float* __restrict__ p,
                                                  float* __restrict__ res) {
    __shared__ float row[NU];
    int rowid = blockIdx.x;          // a*NV + v
    int u = threadIdx.x;
    int e = rowid * NU + u;
    int v = rowid & (NV - 1);
    float sino = (part[e] + part[NRAYS + e]) * F_STEP;
    double du = (double)u - 64.0;
    double dv = (double)v - 32.0;
    float cw = (float)(512.0 / sqrt(262144.0 + dv * dv + du * du));
    row[u] = (sino - p[e]) * cw;
    __syncthreads();
    float acc = 0.125f * row[u];
#pragma unroll
    for (int d = 1; d <= 63; d += 2) {
        float f = (float)(-0.5 / (M_PI * M_PI * (double)(d * d)));
        float lo = (u - d >= 0) ? row[u - d] : 0.0f;
        float hi = (u + d < NU) ? row[u + d] : 0.0f;
        acc += f * (lo + hi);
    }
    res[e] = acc;
}

// ---------------- back projection: lanes = v, z-binned column gather ----------------
// Wave = one xy-column; lane = detector row v. For each (a,u) in the column's
// u-window, EVERY lane has ~1.3 candidate samples (xy-weights are ~v-independent),
// so all control flow is wave-uniform: u-bounds, slab t-window (4 rcps) shared by
// all 64 lanes. The z hat-weight becomes 2-tap binning into a per-wave LDS
// z-column (ds_add, cone reach |z-31.5|<23 -> indices provably in [8,55]).
#define RES_PITCH 129

__global__ __launch_bounds__(512, 8) void bp_gather5(const float* __restrict__ res,
                                                     float* __restrict__ out) {
    __shared__ float s_res[NV * RES_PITCH];   // 33024 B
    __shared__ float s_acc[8 * 64];           // per-wave z-accumulator columns
    __shared__ float s_tr[64 * 9];            // transpose pad for coalesced writeout

    const int tid  = threadIdx.x;
    const int lane = tid & 63;        // = v
    const int wv   = tid >> 6;        // wave 0..7
    const int y    = blockIdx.x & 127;
    const int x8   = blockIdx.x >> 7;     // 0..15
    const int xi   = x8 * 8 + wv;         // this wave's column x

    const float x0 = (float)xi - 63.5f;
    const float y0 = (float)y  - 63.5f;
    const float vvf = (float)lane - 31.5f;
    const float s2  = fmaf(vvf, vvf, 262144.0f);   // vv^2 + 512^2 (per-lane const)
    const v2f vv2   = {vvf, vvf};

    s_acc[tid] = 0.0f;                // 8*64 == 512

    for (int a = 0; a < NA; ++a) {
        __syncthreads();
        const float* ra = res + a * (NV * NU);
#pragma unroll
        for (int k = 0; k < 16; ++k) {
            int e = tid + (k << 9);
            s_res[(e >> 7) * RES_PITCH + (e & 127)] = ra[e];
        }
        __syncthreads();

        float ang = (float)((double)a * (15.0 * M_PI / 180.0));
        const float c  = cosf(ang);
        const float sn = sinf(ang);
        const float c512 = 512.0f * c;
        const float s512 = 512.0f * sn;
        const float ab1  = fabsf(c) + fabsf(sn);

        const float Vx  = x0 + 256.0f * c;       // column-uniform
        const float Vy  = y0 + 256.0f * sn;
        const float rho = fmaf(Vx, c, Vy * sn);  // = 256 + x0 c + y0 s  (>166)
        const float tvlo = (rho - ab1) * (1.0f / 512.0f);
        const float tvhi = (rho + ab1) * (1.0f / 512.0f);
        // u-window: uu in 512*(yp +- ab1)/(rho -+ ab1)
        const float yp = y0 * c - x0 * sn;
        const float rlo = __builtin_amdgcn_rcpf(rho - ab1);
        const float rhi = __builtin_amdgcn_rcpf(rho + ab1);
        const float A = yp - ab1, B = yp + ab1;
        const float uumin = 512.0f * A * ((A >= 0.0f) ? rhi : rlo);
        const float uumax = 512.0f * B * ((B >= 0.0f) ? rlo : rhi);
        const int u_lo = max(0,   (int)ceilf(uumin + 63.49f));
        const int u_hi = min(127, (int)floorf(uumax + 63.51f));

        const float Vxm = Vx - 1.0f, Vxp = Vx + 1.0f;
        const float Vym = Vy - 1.0f, Vyp = Vy + 1.0f;
        const v2f mVx = {-Vx, -Vx}, mVy = {-Vy, -Vy};
        float* accw = s_acc + (wv << 6);

        float uuf = (float)u_lo - 63.5f;
        for (int u = u_lo; u <= u_hi; ++u, uuf += 1.0f) {
            // ---- wave-uniform u setup ----
            const float pu = fmaf(-uuf, sn, c512);
            const float qu = fmaf(uuf, c, s512);
            const float rp = __builtin_amdgcn_rcpf(pu);
            const float rq = __builtin_amdgcn_rcpf(qu);
            const float ax = Vxm * rp, bx = Vxp * rp;
            const float ay = Vym * rq, by = Vyp * rq;
            const float tl = fmaxf(fmaxf(fminf(ax, bx), fminf(ay, by)), tvlo);
            const float th = fminf(fminf(fmaxf(ax, bx), fmaxf(ay, by)), tvhi);
            if (tl >= th) continue;           // wave-uniform branch
            const float tlDL = tl * INV_DL;
            const v2f pu2 = {pu, pu}, qu2 = {qu, qu};

            // ---- per-lane (v = lane) ----
            const float rv   = s_res[lane * RES_PITCH + u];
            const float arg  = fmaf(uuf, uuf, s2);
            const float invn = __builtin_amdgcn_rsqf(arg);
            const float nn   = arg * invn;                 // sqrt(arg)
            // 2 candidate ell grid points from the window start (width <= 1.81 steps)
            const float i0f  = ceilf(fmaf(tlDL, nn, -(F_L0 * INV_DL) - 1.0e-3f));
            const float ell0 = fmaf(i0f, F_DL, F_L0);
            v2f tp;
            tp.x = ell0 * invn;
            tp.y = fmaf(F_DL, invn, tp.x);
            const v2f one2 = {1.0f, 1.0f}, zero2 = {0.0f, 0.0f};
            v2f wx = __builtin_elementwise_max(
                one2 - __builtin_elementwise_abs(__builtin_elementwise_fma(tp, pu2, mVx)), zero2);
            v2f wy = __builtin_elementwise_max(
                one2 - __builtin_elementwise_abs(__builtin_elementwise_fma(tp, qu2, mVy)), zero2);
            v2f val = wx * wy;
            const v2f rv2 = {rv, rv};
            val = val * rv2;
            // z positions (volume float index); cone reach keeps iz in [8,55)
            v2f fz = __builtin_elementwise_fma(tp, vv2, (v2f){31.5f, 31.5f});
            const float zf0 = floorf(fz.x), zf1 = floorf(fz.y);
            const float fr0 = fz.x - zf0,   fr1 = fz.y - zf1;
            const int iz0 = (int)zf0, iz1 = (int)zf1;
            atomicAdd(&accw[iz0],     val.x * (1.0f - fr0));
            atomicAdd(&accw[iz0 + 1], val.x * fr0);
            atomicAdd(&accw[iz1],     val.y * (1.0f - fr1));
            atomicAdd(&accw[iz1 + 1], val.y * fr1);
        }
    }
    __syncthreads();

    // transpose for coalesced writeout: s_tr[z][xo]
    s_tr[lane * 9 + wv] = s_acc[(wv << 6) + lane] * F_STEP;   // LAMB = 1
    __syncthreads();
    const int z  = tid >> 3;
    const int xo = tid & 7;
    out[(z << 14) + (y << 7) + x8 * 8 + xo] = s_tr[z * 9 + xo];
}

extern "C" void kernel_launch(void* const* d_in, const int* in_sizes, int n_in,
                              void* d_out, int out_size, void* d_ws, size_t ws_size,
                              hipStream_t stream) {
    const float* x = (const float*)d_in[0];   // [1,1,64,128,128]
    const float* p = (const float*)d_in[1];   // [1,1,24,64,128]
    float* out  = (float*)d_out;              // [1,1,64,128,128]
    float* res  = (float*)d_ws;               // filtered residual, NRAYS floats
    float* part = res + NRAYS;                // 2 FP segments, 2*NRAYS floats

    dim3 fpg(NRAYS / 256, 2);
    fp_seg_kernel<<<fpg, 256, 0, stream>>>(x, part);
    ramp_kernel<<<NA * NV, NU, 0, stream>>>(part, p, res);
    bp_gather5<<<16 * 128, 512, 0, stream>>>(res, out);
}

// Round 8
// 626.927 us; speedup vs baseline: 5.7469x; 3.4401x over previous
//
#include <hip/hip_runtime.h>
#include <math.h>

// ---- geometry constants (match reference) ----
#define NA   24
#define NU   128
#define NV   64
#define NW   128   // volume W (x)
#define NH   128   // volume H (y)
#define ND   64    // volume D (z)
#define NS   128   // samples per ray
#define F_STEP 1.5625f            // 2*HS/S = 200/128
#define F_DL  (200.0f / 127.0f)   // linspace(156,356,128) spacing
#define F_L0  156.0f
#define INV_DL (127.0f / 200.0f)

#define NRAYS (NA * NV * NU)      // 196608
#define VOX   (NW * NH * ND)      // 1048576

typedef float v2f __attribute__((ext_vector_type(2)));

// Per-ray geometry for FP.
__device__ __forceinline__ void ray_setup(int a, int v, int u,
                                          float& sx, float& sy,
                                          float& dx, float& dy, float& dz) {
    float ang = (float)((double)a * (15.0 * M_PI / 180.0));
    float c = cosf(ang), s = sinf(ang);
    float uu = (float)u - 63.5f;
    float vv = (float)v - 31.5f;
    float ux = 512.0f * c - uu * s;
    float uy = 512.0f * s + uu * c;
    float uz = vv;
    float invn = 1.0f / sqrtf(ux * ux + uy * uy + uz * uz);
    dx = ux * invn; dy = uy * invn; dz = uz * invn;
    sx = -256.0f * c; sy = -256.0f * s;
}

// ---------------- forward projection, segmented over ell ----------------
__global__ __launch_bounds__(256) void fp_seg_kernel(const float* __restrict__ vol,
                                                     float* __restrict__ part) {
    int r = blockIdx.x * blockDim.x + threadIdx.x;
    int seg = blockIdx.y;
    int u = r & (NU - 1);
    int v = (r >> 7) & (NV - 1);
    int a = r >> 13;

    float sx, sy, dx, dy, dz;
    ray_setup(a, v, u, sx, sy, dx, dy, dz);

    float rx = 1.0f / dx, ry = 1.0f / dy, rz = 1.0f / dz;
    float ex0 = (-64.55f - sx) * rx, ex1 = (64.55f - sx) * rx;
    float ey0 = (-64.55f - sy) * ry, ey1 = (64.55f - sy) * ry;
    float ez0 = (-32.55f) * rz,      ez1 = (32.55f) * rz;
    float llo = fmaxf(fmaxf(fminf(ex0, ex1), fminf(ey0, ey1)), fminf(ez0, ez1));
    float lhi = fminf(fminf(fmaxf(ex0, ex1), fmaxf(ey0, ey1)), fmaxf(ez0, ez1));
    int i_lo = max(seg * 64,      (int)ceilf((llo - F_L0) * INV_DL));
    int i_hi = min(seg * 64 + 63, (int)floorf((lhi - F_L0) * INV_DL));

    float acc = 0.0f;
    for (int i = i_lo; i <= i_hi; ++i) {
        float ell = F_L0 + F_DL * (float)i;
        float cx = sx + ell * dx + 63.5f;
        float cy = sy + ell * dy + 63.5f;
        float cz =      ell * dz + 31.5f;
        float fx = floorf(cx), fy = floorf(cy), fz = floorf(cz);
        int ix = (int)fx, iy = (int)fy, iz = (int)fz;
        float wx1 = cx - fx, wy1 = cy - fy, wz1 = cz - fz;
        float wx0 = 1.0f - wx1, wy0 = 1.0f - wy1, wz0 = 1.0f - wz1;
        bool bx0 = (unsigned)ix < NW,      bx1 = (unsigned)(ix + 1) < NW;
        bool by0 = (unsigned)iy < NH,      by1 = (unsigned)(iy + 1) < NH;
        bool bz0 = (unsigned)iz < ND,      bz1 = (unsigned)(iz + 1) < ND;
        long base = ((long)iz * NH + iy) * NW + ix;
        float v000 = (bz0 && by0 && bx0) ? vol[base]                 : 0.0f;
        float v001 = (bz0 && by0 && bx1) ? vol[base + 1]             : 0.0f;
        float v010 = (bz0 && by1 && bx0) ? vol[base + NW]            : 0.0f;
        float v011 = (bz0 && by1 && bx1) ? vol[base + NW + 1]        : 0.0f;
        float v100 = (bz1 && by0 && bx0) ? vol[base + NH * NW]       : 0.0f;
        float v101 = (bz1 && by0 && bx1) ? vol[base + NH * NW + 1]   : 0.0f;
        float v110 = (bz1 && by1 && bx0) ? vol[base + NH * NW + NW]  : 0.0f;
        float v111 = (bz1 && by1 && bx1) ? vol[base + NH * NW + NW + 1] : 0.0f;
        acc += wz0 * (wy0 * (wx0 * v000 + wx1 * v001) +
                      wy1 * (wx0 * v010 + wx1 * v011)) +
               wz1 * (wy0 * (wx0 * v100 + wx1 * v101) +
                      wy1 * (wx0 * v110 + wx1 * v111));
    }
    part[seg * NRAYS + r] = acc;
}

// ---------------- residual + cosine weight + Ram-Lak along u ----------------
__global__ __launch_bounds__(NU) void ramp_kernel(const float* __restrict__ part,
                                                  const float* __restrict__ p,
                                                  float* __restrict__ res) {
    __shared__ float row[NU];
    int rowid = blockIdx.x;          // a*NV + v
    int u = threadIdx.x;
    int e = rowid * NU + u;
    int v = rowid & (NV - 1);
    float sino = (part[e] + part[NRAYS + e]) * F_STEP;
    double du = (double)u - 64.0;
    double dv = (double)v - 32.0;
    float cw = (float)(512.0 / sqrt(262144.0 + dv * dv + du * du));
    row[u] = (sino - p[e]) * cw;
    __syncthreads();
    float acc = 0.125f * row[u];
#pragma unroll
    for (int d = 1; d <= 63; d += 2) {
        float f = (float)(-0.5 / (M_PI * M_PI * (double)(d * d)));
        float lo = (u - d >= 0) ? row[u - d] : 0.0f;
        float hi = (u + d < NU) ? row[u + d] : 0.0f;
        acc += f * (lo + hi);
    }
    res[e] = acc;
}

// ---------------- back projection: lanes = v, register z-splat ----------------
// Wave = one xy-column; lane = detector row v. Per (col, angle) the candidate
// t-range has width <= 0.0117, so each lane's deposit positions fz = t*vv+31.5
// span <= 0.37 voxels -> at most 3 z-cells. Accumulate the whole u-loop into 4
// STATIC register bins D0..D3 at base izb = floor(Zmin) via the linear splat
// identity (bin j += max(0, 1-|fz-(izb+j)|) * val), then ONE 4-tap LDS
// deposit per (col,angle). All control flow wave-uniform; every lane genuine.
#define RES_PITCH 129

__global__ __launch_bounds__(512, 8) void bp_gather6(const float* __restrict__ res,
                                                     float* __restrict__ out) {
    __shared__ float s_res[NV * RES_PITCH];   // 33024 B
    __shared__ float s_acc[8 * 64];           // per-wave z-accumulator columns

    const int tid  = threadIdx.x;
    const int lane = tid & 63;        // = v
    const int wv   = tid >> 6;        // wave 0..7
    const int y    = blockIdx.x >> 4;     // 0..127
    const int x16  = blockIdx.x & 15;     // 0..15
    const int xi   = x16 + 16 * wv;       // waves span full x-range -> balance

    const float x0 = (float)xi - 63.5f;
    const float y0 = (float)y  - 63.5f;
    const float vvf = (float)lane - 31.5f;
    const float s2  = fmaf(vvf, vvf, 262144.0f);   // vv^2 + 512^2
    const v2f vv2   = {vvf, vvf};
    const v2f one2  = {1.0f, 1.0f}, zero2 = {0.0f, 0.0f};

    s_acc[tid] = 0.0f;                // 8*64 == 512

    for (int a = 0; a < NA; ++a) {
        __syncthreads();
        const float* ra = res + (a << 13);
#pragma unroll
        for (int k = 0; k < 16; ++k) {
            int e = tid + (k << 9);
            s_res[(e >> 7) * RES_PITCH + (e & 127)] = ra[e];
        }
        __syncthreads();

        float ang = (float)((double)a * (15.0 * M_PI / 180.0));
        const float c  = cosf(ang);
        const float sn = sinf(ang);
        const float c512 = 512.0f * c;
        const float s512 = 512.0f * sn;
        const float ab1  = fabsf(c) + fabsf(sn);

        const float Vx  = x0 + 256.0f * c;       // column-uniform
        const float Vy  = y0 + 256.0f * sn;
        const float rho = fmaf(x0, c, fmaf(y0, sn, 256.0f));   // in [166, 346]
        const float tvlo = (rho - ab1) * (1.0f / 512.0f);
        const float tvhi = (rho + ab1) * (1.0f / 512.0f);
        // u-window (wave-uniform)
        const float yp = y0 * c - x0 * sn;
        const float rlo = __builtin_amdgcn_rcpf(rho - ab1);
        const float rhi = __builtin_amdgcn_rcpf(rho + ab1);
        const float A = yp - ab1, B = yp + ab1;
        const float uumin = 512.0f * A * ((A >= 0.0f) ? rhi : rlo);
        const float uumax = 512.0f * B * ((B >= 0.0f) ? rlo : rhi);
        const int u_lo = max(0,   (int)ceilf(uumin + 63.49f));
        const int u_hi = min(127, (int)floorf(uumax + 63.51f));
        if (u_lo > u_hi) continue;

        // per-lane static z-bin base: all deposits lie in [izb, izb+3]
        const float tloM = tvlo - 2.0e-4f;
        const float thiM = tvhi + 6.5e-3f;     // + 2 ell-steps * invn + slack
        const float Zmin = fmaf(vvf, (vvf >= 0.0f) ? tloM : thiM, 31.5f);
        const float izbf = floorf(Zmin);       // in [8, 53] (cone reach)
        const int   izb  = (int)izbf;
        const v2f b0 = {izbf, izbf};

        v2f D0 = zero2, D1 = zero2, D2 = zero2, D3 = zero2;

        const float Vxm = Vx - 1.0f, Vxp = Vx + 1.0f;
        const float Vym = Vy - 1.0f, Vyp = Vy + 1.0f;
        const v2f mVx = {-Vx, -Vx}, mVy = {-Vy, -Vy};

        float uuf = (float)u_lo - 63.5f;
        for (int u = u_lo; u <= u_hi; ++u, uuf += 1.0f) {
            // ---- wave-uniform u setup ----
            const float pu = fmaf(-uuf, sn, c512);
            const float qu = fmaf(uuf, c, s512);
            const float rp = __builtin_amdgcn_rcpf(pu);
            const float rq = __builtin_amdgcn_rcpf(qu);
            const float ax = Vxm * rp, bx = Vxp * rp;
            const float ay = Vym * rq, by = Vyp * rq;
            const float tl = fmaxf(fmaxf(fminf(ax, bx), fminf(ay, by)), tvlo);
            const float th = fminf(fminf(fmaxf(ax, bx), fmaxf(ay, by)), tvhi);
            if (tl >= th) continue;           // wave-uniform branch
            const float tlDL = tl * INV_DL;
            const v2f pu2 = {pu, pu}, qu2 = {qu, qu};

            // ---- per-lane (v = lane): 2 candidate samples ----
            const float rv   = s_res[lane * RES_PITCH + u];
            const float arg  = fmaf(uuf, uuf, s2);
            const float invn = __builtin_amdgcn_rsqf(arg);
            const float nn   = arg * invn;                 // sqrt(arg)
            const float i0f  = ceilf(fmaf(tlDL, nn, -(F_L0 * INV_DL) - 1.0e-3f));
            const float ell0 = fmaf(i0f, F_DL, F_L0);
            v2f tp;
            tp.x = ell0 * invn;
            tp.y = fmaf(F_DL, invn, tp.x);
            v2f wx = __builtin_elementwise_max(
                one2 - __builtin_elementwise_abs(__builtin_elementwise_fma(tp, pu2, mVx)), zero2);
            v2f wy = __builtin_elementwise_max(
                one2 - __builtin_elementwise_abs(__builtin_elementwise_fma(tp, qu2, mVy)), zero2);
            v2f val = wx * wy;
            const v2f rv2 = {rv, rv};
            val = val * rv2;
            // z-splat into 4 static bins (exact: true cells subset of izb..izb+3)
            const v2f fz2 = __builtin_elementwise_fma(tp, vv2, (v2f){31.5f, 31.5f});
            const v2f g = fz2 - b0;                        // in [0, ~1.4)
            D0 = __builtin_elementwise_fma(__builtin_elementwise_max(
                     one2 - __builtin_elementwise_abs(g), zero2), val, D0);
            D1 = __builtin_elementwise_fma(__builtin_elementwise_max(
                     one2 - __builtin_elementwise_abs(g - one2), zero2), val, D1);
            D2 = __builtin_elementwise_fma(__builtin_elementwise_max(
                     one2 - __builtin_elementwise_abs(g - (v2f){2.0f, 2.0f}), zero2), val, D2);
            D3 = __builtin_elementwise_fma(__builtin_elementwise_max(
                     one2 - __builtin_elementwise_abs(g - (v2f){3.0f, 3.0f}), zero2), val, D3);
        }

        // one 4-tap LDS deposit per (col, angle); wave-private column
        float* accw = s_acc + (wv << 6);
        atomicAdd(&accw[izb],     D0.x + D0.y);
        atomicAdd(&accw[izb + 1], D1.x + D1.y);
        atomicAdd(&accw[izb + 2], D2.x + D2.y);
        atomicAdd(&accw[izb + 3], D3.x + D3.y);
    }
    __syncthreads();

    // writeout: thread -> (z, wave-slot)
    const int z  = tid >> 3;
    const int w8 = tid & 7;
    out[(z << 14) + (y << 7) + x16 + 16 * w8] = s_acc[(w8 << 6) + z] * F_STEP;
}

extern "C" void kernel_launch(void* const* d_in, const int* in_sizes, int n_in,
                              void* d_out, int out_size, void* d_ws, size_t ws_size,
                              hipStream_t stream) {
    const float* x = (const float*)d_in[0];   // [1,1,64,128,128]
    const float* p = (const float*)d_in[1];   // [1,1,24,64,128]
    float* out  = (float*)d_out;              // [1,1,64,128,128]
    float* res  = (float*)d_ws;               // filtered residual, NRAYS floats
    float* part = res + NRAYS;                // 2 FP segments, 2*NRAYS floats

    dim3 fpg(NRAYS / 256, 2);
    fp_seg_kernel<<<fpg, 256, 0, stream>>>(x, part);
    ramp_kernel<<<NA * NV, NU, 0, stream>>>(part, p, res);
    bp_gather6<<<16 * 128, 512, 0, stream>>>(res, out);
}